// Round 7
// baseline (272.255 us; speedup 1.0000x reference)
//
#include <hip/hip_runtime.h>

#define TPB 256
#define TE  2048      // edges per binscatter block
#define MAXB 6144     // fixed bucket capacity (mean 4081, 32 sigma headroom); mult of 8

typedef _Float16 half_t;
typedef _Float16 half4 __attribute__((ext_vector_type(4)));
typedef _Float16 half8 __attribute__((ext_vector_type(8)));
typedef float float8v __attribute__((ext_vector_type(8)));
typedef float f32x4 __attribute__((ext_vector_type(4)));

static inline int cdiv(int a, int b) { return (a + b - 1) / b; }

// r5: scattered 4B stores ~16x write-amplified -> contiguous runs only.
// r12: fixed-capacity buckets kill histogram+scans.
// r14: software grid barriers cost ~100us (L2 wb/inv, non-coherent XCD L2s).
// r15: conv3_head VALU matmul -> MFMA f32_16x16x32_f16 (62.8 -> 45.4us).
// r16: 9.4M LDS conflicts were per-block weight-transpose staging -> global
//      pre-transposed half [col][k] tables; LDS 21.3KB; bounds (256,6).
// r17: transpose as asymmetric extra binscatter block perturbed scheduling
//      differently under graph replay -> bit divergence (tripwire).
// r18 (R5+R6 root cause): edge order = ATOMIC ARRIVAL ORDER -> fp32 sum order
//      -> f16 rounding flips; error ranged 4.9e-4..2.9e-3 across schedules.
//      Fix: k_csr sorts each node's staged list by src id (owner thread,
//      insertion sort in LDS). ssrc becomes canonical; everything downstream
//      is atomic-free -> whole pipeline bit-deterministic.

// one-time weight transpose+convert to half [col][k]; 2 uniform blocks
__global__ void __launch_bounds__(TPB)
k_wprep(const float* __restrict__ W3, const float* __restrict__ Wl1,
        half_t* __restrict__ w3t, half_t* __restrict__ w1t) {
    const int tid = threadIdx.x;
    if (blockIdx.x == 0) {
        for (int t = tid; t < 128 * 16; t += TPB) {       // W3: 64k x 128c
            int c = t >> 4, k4 = t & 15;
            half4 h;
#pragma unroll
            for (int i = 0; i < 4; ++i) h[i] = (half_t)W3[(k4 * 4 + i) * 128 + c];
            *(half4*)&w3t[c * 64 + k4 * 4] = h;
        }
    } else {
        for (int t = tid; t < 64 * 32; t += TPB) {        // Wl1: 128k x 64c
            int c = t >> 5, k4 = t & 31;
            half4 h;
#pragma unroll
            for (int i = 0; i < 4; ++i) h[i] = (half_t)Wl1[(k4 * 4 + i) * 64 + c];
            *(half4*)&w1t[c * 128 + k4 * 4] = h;
        }
    }
}

__global__ void __launch_bounds__(TPB)
k_binscatter(const int* __restrict__ src, const int* __restrict__ dst,
             int* __restrict__ bcur, int* __restrict__ ncnt,
             unsigned int* __restrict__ gbuf, int e, int nb) {
    __shared__ int lcnt[256], loffs[256], lcur[256], gres[256];
    __shared__ int ss[256];
    __shared__ unsigned int ldata[TE];
    const int tid = threadIdx.x;
    const int base = blockIdx.x * TE;
    const int cnt = min(TE, e - base);
    lcnt[tid] = 0;
    __syncthreads();

    unsigned int myv[TE / TPB];
    int myb[TE / TPB];
#pragma unroll
    for (int k = 0; k < TE / TPB; ++k) {
        int j = tid + k * TPB;
        if (j < cnt) {
            int d = dst[base + j], s = src[base + j];
            int b = d >> 8;
            myv[k] = ((unsigned)b << 24) | ((unsigned)(d & 255) << 16) | (unsigned)s;
            myb[k] = b;
            atomicAdd(&lcnt[b], 1);
            atomicAdd(&ncnt[d], 1);          // global per-node in-degree
        } else myb[k] = -1;
    }
    __syncthreads();
    {
        int v = lcnt[tid];
        ss[tid] = v;
        __syncthreads();
        for (int d = 1; d < 256; d <<= 1) {
            int x2 = (tid >= d) ? ss[tid - d] : 0;
            __syncthreads();
            ss[tid] += x2;
            __syncthreads();
        }
        loffs[tid] = ss[tid] - v;
        lcur[tid] = ss[tid] - v;
    }
    __syncthreads();
    if (tid < nb && lcnt[tid])
        gres[tid] = tid * MAXB + atomicAdd(&bcur[tid], lcnt[tid]);
#pragma unroll
    for (int k = 0; k < TE / TPB; ++k) {
        if (myb[k] >= 0) {
            int p = atomicAdd(&lcur[myb[k]], 1);
            ldata[p] = myv[k];
        }
    }
    __syncthreads();
    for (int j = tid; j < cnt; j += TPB) {        // contiguous per-bucket runs
        unsigned int v = ldata[j];
        int b = v >> 24;
        gbuf[gres[b] + (j - loffs[b])] = v & 0xFFFFFFu;
    }
}

// per-bucket CSR from precomputed degrees: ONE pass over bucket edges.
// r18: per-node lists sorted by src id -> canonical ssrc, bit-determinism.
__global__ void __launch_bounds__(TPB)
k_csr(const unsigned int* __restrict__ gbuf, const int* __restrict__ bcur,
      const int* __restrict__ ncnt, const float* __restrict__ x,
      int* __restrict__ offs, unsigned short* __restrict__ nch,
      float* __restrict__ dinv, unsigned short* __restrict__ ssrc,
      half_t* __restrict__ G, int n, int nb) {
    __shared__ int ss[256], lcur2[256];
    __shared__ float sdinv[256];
    __shared__ unsigned short stage[MAXB];
    const int b = blockIdx.x;
    const int t = threadIdx.x;
    const int s0 = b * MAXB;
    const int m = bcur[b];

    const int v = ncnt[b * 256 + t];              // in-degree (excl self-loop)
    const int pv = (v + 7) & ~7;                  // pad to 8
    ss[t] = pv;
    __syncthreads();
    for (int d = 1; d < 256; d <<= 1) {
        int x2 = (t >= d) ? ss[t - d] : 0;
        __syncthreads();
        ss[t] += x2;
        __syncthreads();
    }
    const int lo = ss[t] - pv;
    lcur2[t] = lo;
    float di = rsqrtf((float)v + 1.0f);           // +1 self-loop
    sdinv[t] = di;
    int node = b * 256 + t;
    if (node < n) {
        offs[node] = s0 + lo;
        nch[node] = (unsigned short)(pv >> 3);
        dinv[node] = di;
    }
    __syncthreads();
    for (int j = t; j < m; j += TPB) {
        unsigned int u = gbuf[s0 + j];
        int p = atomicAdd(&lcur2[(u >> 16) & 255], 1);
        stage[p] = (unsigned short)(u & 0xFFFFu);
    }
    __syncthreads();
    {   // canonical order: owner thread insertion-sorts its node's list by
        // src id -- kills all atomic-arrival-order nondeterminism downstream
        for (int q = lo + 1; q < lo + v; ++q) {
            unsigned short key = stage[q];
            int w = q - 1;
            while (w >= lo && stage[w] > key) { stage[w + 1] = stage[w]; --w; }
            stage[w + 1] = key;
        }
        for (int q = lo + v; q < lo + pv; ++q)    // sentinel-fill padding
            stage[q] = (unsigned short)n;
    }
    __syncthreads();
    const int tot = ss[255];
    for (int j = t; j < tot; j += TPB) ssrc[s0 + j] = stage[j];

    // fused scale: G16[node] = x[node] * dinv[node], fp32 -> fp16
    const int base = b * 256;
    const int cn = min(256, n - base);
    const float4* X4 = (const float4*)x;
    half4* G4 = (half4*)G;
    for (int j = t; j < cn * 4; j += TPB) {
        int nl = j >> 2, k4 = j & 3;
        float4 vv = X4[(size_t)(base + nl) * 4 + k4];
        float d = sdinv[nl];
        half4 h;
        h.x = (half_t)(vv.x * d); h.y = (half_t)(vv.y * d);
        h.z = (half_t)(vv.z * d); h.w = (half_t)(vv.w * d);
        G4[(size_t)(base + nl) * 4 + k4] = h;
    }
    if (b == 0 && t < 4) G4[(size_t)n * 4 + t] = half4{0, 0, 0, 0};  // sentinel row
}

// ---------------- fused gather + GEMM conv (conv1, conv2) ----------------
template<int DI, int DO, int R, bool SCALE, bool OUT_HALF, bool WHALF, bool ZSENT>
__global__ void __launch_bounds__(TPB, 4)
k_conv(const int* __restrict__ offs, const unsigned short* __restrict__ nch,
       const unsigned short* __restrict__ ssrc,
       const half_t* __restrict__ G, const float* __restrict__ dinv,
       const float* __restrict__ W, const float* __restrict__ b,
       void* __restrict__ outp, int n) {
    constexpr int CT = DO / 4;
    constexpr int RT = TPB / CT;
    constexpr int TM = RT * R;
    constexpr int K4 = DI / 4;
    constexpr int PX = K4 + 1;
    constexpr int C  = DI / 8;
    static_assert(TM * C == TPB, "gather/gemm tile mismatch");
    __shared__ float4 sW4[WHALF ? 1 : DI * CT];
    __shared__ half4  sWh[WHALF ? DI * CT : 1];
    __shared__ float4 sX4[TM * PX];
    __shared__ int soffs[TM];
    __shared__ unsigned short snch[TM];
    const int tid = threadIdx.x;
    const int r0 = blockIdx.x * TM;

    const float4* Wg = (const float4*)W;
    for (int t = tid; t < DI * CT; t += TPB) {
        float4 w = Wg[t];
        if (WHALF) {
            half4 h;
            h.x = (half_t)w.x; h.y = (half_t)w.y;
            h.z = (half_t)w.z; h.w = (half_t)w.w;
            sWh[t] = h;
        } else {
            sW4[t] = w;
        }
    }
    if (tid < TM) {
        int row = r0 + tid;
        soffs[tid] = (row < n) ? offs[row] : 0;
        snch[tid] = (row < n) ? nch[row] : (unsigned short)0;
    }
    __syncthreads();

    {   // ---- gather ----
        int lrow = tid / C;
        int gc = tid - lrow * C;
        int row = r0 + lrow;
        float8v acc;
#pragma unroll
        for (int q = 0; q < 8; ++q) acc[q] = 0.f;
        if (row < n) {
            const half8* Grow = (const half8*)G;
            const unsigned gcU = (unsigned)gc;
            half8 hs = Grow[(unsigned)row * C + gcU];
#pragma unroll
            for (int q = 0; q < 8; ++q) acc[q] = (float)hs[q];
            const int nchunks = snch[lrow];
            const uint4* sv = (const uint4*)(ssrc + soffs[lrow]);
            int k = 0;
            for (; k + 2 <= nchunks; k += 2) {
                uint4 pa = sv[k];
                uint4 pb = sv[k + 1];
                unsigned a0 = pa.x & 0xFFFFu, a1 = pa.x >> 16;
                unsigned a2 = pa.y & 0xFFFFu, a3 = pa.y >> 16;
                unsigned a4 = pa.z & 0xFFFFu, a5 = pa.z >> 16;
                unsigned a6 = pa.w & 0xFFFFu, a7 = pa.w >> 16;
                unsigned b0 = pb.x & 0xFFFFu, b1 = pb.x >> 16;
                unsigned b2 = pb.y & 0xFFFFu, b3 = pb.y >> 16;
                unsigned b4 = pb.z & 0xFFFFu, b5 = pb.z >> 16;
                unsigned b6 = pb.w & 0xFFFFu, b7 = pb.w >> 16;
                half8 ga0 = Grow[a0 * C + gcU];
                half8 ga1 = Grow[a1 * C + gcU];
                half8 ga2 = Grow[a2 * C + gcU];
                half8 ga3 = Grow[a3 * C + gcU];
                half8 ga4 = Grow[a4 * C + gcU];
                half8 ga5 = Grow[a5 * C + gcU];
                half8 ga6 = Grow[a6 * C + gcU];
                half8 ga7 = Grow[a7 * C + gcU];
                half8 gb0 = Grow[b0 * C + gcU];
                half8 gb1 = Grow[b1 * C + gcU];
                half8 gb2 = Grow[b2 * C + gcU];
                half8 gb3 = Grow[b3 * C + gcU];
                half8 gb4 = Grow[b4 * C + gcU];
                half8 gb5 = Grow[b5 * C + gcU];
                half8 gb6 = Grow[b6 * C + gcU];
                half8 gb7 = Grow[b7 * C + gcU];
#pragma unroll
                for (int q = 0; q < 8; ++q)
                    acc[q] += (((((float)ga0[q] + (float)ga1[q]) + ((float)ga2[q] + (float)ga3[q]))
                             +  (((float)ga4[q] + (float)ga5[q]) + ((float)ga6[q] + (float)ga7[q])))
                             + ((((float)gb0[q] + (float)gb1[q]) + ((float)gb2[q] + (float)gb3[q]))
                             +  (((float)gb4[q] + (float)gb5[q]) + ((float)gb6[q] + (float)gb7[q]))));
            }
            if (k < nchunks) {
                uint4 pk = sv[k];
                unsigned a0 = pk.x & 0xFFFFu, a1 = pk.x >> 16;
                unsigned a2 = pk.y & 0xFFFFu, a3 = pk.y >> 16;
                unsigned a4 = pk.z & 0xFFFFu, a5 = pk.z >> 16;
                unsigned a6 = pk.w & 0xFFFFu, a7 = pk.w >> 16;
                half8 g0 = Grow[a0 * C + gcU];
                half8 g1 = Grow[a1 * C + gcU];
                half8 g2 = Grow[a2 * C + gcU];
                half8 g3 = Grow[a3 * C + gcU];
                half8 g4 = Grow[a4 * C + gcU];
                half8 g5 = Grow[a5 * C + gcU];
                half8 g6 = Grow[a6 * C + gcU];
                half8 g7 = Grow[a7 * C + gcU];
#pragma unroll
                for (int q = 0; q < 8; ++q)
                    acc[q] += (((float)g0[q] + (float)g1[q]) + ((float)g2[q] + (float)g3[q]))
                            + (((float)g4[q] + (float)g5[q]) + ((float)g6[q] + (float)g7[q]));
            }
            float di = dinv[row];
#pragma unroll
            for (int q = 0; q < 8; ++q) acc[q] *= di;
        }
        sX4[lrow * PX + 2 * gc]     = make_float4(acc[0], acc[1], acc[2], acc[3]);
        sX4[lrow * PX + 2 * gc + 1] = make_float4(acc[4], acc[5], acc[6], acc[7]);
    }
    __syncthreads();

    // ---- GEMM ----
    const int c = tid & (CT - 1);
    const int rg = tid / CT;
    const int rbase = rg * R;
    float4 acc[R];
#pragma unroll
    for (int r = 0; r < R; ++r) acc[r] = make_float4(0.f, 0.f, 0.f, 0.f);
#pragma unroll 2
    for (int k4 = 0; k4 < K4; ++k4) {
        float4 xv[R];
#pragma unroll
        for (int r = 0; r < R; ++r) xv[r] = sX4[(rbase + r) * PX + k4];
#pragma unroll
        for (int kk = 0; kk < 4; ++kk) {
            float4 wv;
            if (WHALF) {
                half4 wh = sWh[(k4 * 4 + kk) * CT + c];
                wv = make_float4((float)wh.x, (float)wh.y, (float)wh.z, (float)wh.w);
            } else {
                wv = sW4[(k4 * 4 + kk) * CT + c];
            }
#pragma unroll
            for (int r = 0; r < R; ++r) {
                float xs = (kk == 0) ? xv[r].x : (kk == 1) ? xv[r].y
                         : (kk == 2) ? xv[r].z : xv[r].w;
                acc[r].x += xs * wv.x; acc[r].y += xs * wv.y;
                acc[r].z += xs * wv.z; acc[r].w += xs * wv.w;
            }
        }
    }

    float4 bc = ((const float4*)b)[c];
#pragma unroll
    for (int r = 0; r < R; ++r) {
        int row = r0 + rbase + r;
        if (row < n) {
            float4 o;
            o.x = fmaxf(acc[r].x + bc.x, 0.f);
            o.y = fmaxf(acc[r].y + bc.y, 0.f);
            o.z = fmaxf(acc[r].z + bc.z, 0.f);
            o.w = fmaxf(acc[r].w + bc.w, 0.f);
            if (SCALE) {
                float d = dinv[row];
                o.x *= d; o.y *= d; o.z *= d; o.w *= d;
            }
            if (OUT_HALF) {
                half4 h;
                h.x = (half_t)o.x; h.y = (half_t)o.y;
                h.z = (half_t)o.z; h.w = (half_t)o.w;
                ((half4*)outp)[(size_t)row * CT + c] = h;
            } else {
                ((float4*)outp)[(size_t)row * CT + c] = o;
            }
        }
    }
    if (ZSENT && OUT_HALF && blockIdx.x == 0 && tid < CT)
        ((half4*)outp)[(size_t)n * CT + tid] = half4{0, 0, 0, 0};
}

// ---------------- conv3 (64->128, MFMA) + fused dense head (stage1 MFMA) ----------------
// B fragments read directly from pre-transposed global half tables (L2-hit
// broadcast); LDS holds only X16/X3/h1/h2 -> 21.3KB -> 6 blocks/CU.
__global__ void __launch_bounds__(TPB, 6)
k_conv3_head(const int* __restrict__ offs, const unsigned short* __restrict__ nch,
             const unsigned short* __restrict__ ssrc,
             const half_t* __restrict__ G, const float* __restrict__ dinv,
             const half_t* __restrict__ w3t, const float* __restrict__ b,
             const half_t* __restrict__ w1t, const float* __restrict__ bl1,
             const float* __restrict__ Wl2, const float* __restrict__ bl2,
             const float* __restrict__ Wl3, const float* __restrict__ bl3,
             float* __restrict__ out, int n) {
    constexpr int TM = 32;           // rows per block
    constexpr int C  = 8;            // gather: half8 chunks per 64-dim row
    constexpr int XPA = 72;          // X16 pitch (halfs): 144B
    constexpr int XPB = 136;         // X3 pitch (halfs): 272B
    __shared__ __align__(16) union {
        struct { half_t X16[TM * XPA]; } g;                               // 4.6 KB
        struct { half_t X3[TM * XPB]; float h1[TM * 65]; float h2[TM * 33]; } h; // 21.2 KB
    } S;
    __shared__ int soffs[TM];
    __shared__ unsigned short snch[TM];
    const int tid = threadIdx.x;
    const int r0 = blockIdx.x * TM;
    const int lane = tid & 63;
    const int wv = tid >> 6;         // wave 0..3
    const int lr = lane & 15;        // A-row / B-col / D-col index
    const int kq = lane >> 4;        // k-quarter

    if (tid < TM) {
        int row = r0 + tid;
        soffs[tid] = (row < n) ? offs[row] : 0;
        snch[tid] = (row < n) ? nch[row] : (unsigned short)0;
    }
    __syncthreads();

    {   // ---- gather (DI=64) -> X16 f16 ----
        int lrow = tid / C;
        int gc = tid - lrow * C;
        int row = r0 + lrow;
        float8v acc;
#pragma unroll
        for (int q = 0; q < 8; ++q) acc[q] = 0.f;
        if (row < n) {
            const half8* Grow = (const half8*)G;
            const unsigned gcU = (unsigned)gc;
            half8 hs = Grow[(unsigned)row * C + gcU];
#pragma unroll
            for (int q = 0; q < 8; ++q) acc[q] = (float)hs[q];
            const int nchunks = snch[lrow];
            const uint4* sv = (const uint4*)(ssrc + soffs[lrow]);
            int k = 0;
            for (; k + 2 <= nchunks; k += 2) {
                uint4 pa = sv[k];
                uint4 pb = sv[k + 1];
                unsigned a0 = pa.x & 0xFFFFu, a1 = pa.x >> 16;
                unsigned a2 = pa.y & 0xFFFFu, a3 = pa.y >> 16;
                unsigned a4 = pa.z & 0xFFFFu, a5 = pa.z >> 16;
                unsigned a6 = pa.w & 0xFFFFu, a7 = pa.w >> 16;
                unsigned b0 = pb.x & 0xFFFFu, b1 = pb.x >> 16;
                unsigned b2 = pb.y & 0xFFFFu, b3 = pb.y >> 16;
                unsigned b4 = pb.z & 0xFFFFu, b5 = pb.z >> 16;
                unsigned b6 = pb.w & 0xFFFFu, b7 = pb.w >> 16;
                half8 ga0 = Grow[a0 * C + gcU];
                half8 ga1 = Grow[a1 * C + gcU];
                half8 ga2 = Grow[a2 * C + gcU];
                half8 ga3 = Grow[a3 * C + gcU];
                half8 ga4 = Grow[a4 * C + gcU];
                half8 ga5 = Grow[a5 * C + gcU];
                half8 ga6 = Grow[a6 * C + gcU];
                half8 ga7 = Grow[a7 * C + gcU];
                half8 gb0 = Grow[b0 * C + gcU];
                half8 gb1 = Grow[b1 * C + gcU];
                half8 gb2 = Grow[b2 * C + gcU];
                half8 gb3 = Grow[b3 * C + gcU];
                half8 gb4 = Grow[b4 * C + gcU];
                half8 gb5 = Grow[b5 * C + gcU];
                half8 gb6 = Grow[b6 * C + gcU];
                half8 gb7 = Grow[b7 * C + gcU];
#pragma unroll
                for (int q = 0; q < 8; ++q)
                    acc[q] += (((((float)ga0[q] + (float)ga1[q]) + ((float)ga2[q] + (float)ga3[q]))
                             +  (((float)ga4[q] + (float)ga5[q]) + ((float)ga6[q] + (float)ga7[q])))
                             + ((((float)gb0[q] + (float)gb1[q]) + ((float)gb2[q] + (float)gb3[q]))
                             +  (((float)gb4[q] + (float)gb5[q]) + ((float)gb6[q] + (float)gb7[q]))));
            }
            if (k < nchunks) {
                uint4 pk = sv[k];
                unsigned a0 = pk.x & 0xFFFFu, a1 = pk.x >> 16;
                unsigned a2 = pk.y & 0xFFFFu, a3 = pk.y >> 16;
                unsigned a4 = pk.z & 0xFFFFu, a5 = pk.z >> 16;
                unsigned a6 = pk.w & 0xFFFFu, a7 = pk.w >> 16;
                half8 g0 = Grow[a0 * C + gcU];
                half8 g1 = Grow[a1 * C + gcU];
                half8 g2 = Grow[a2 * C + gcU];
                half8 g3 = Grow[a3 * C + gcU];
                half8 g4 = Grow[a4 * C + gcU];
                half8 g5 = Grow[a5 * C + gcU];
                half8 g6 = Grow[a6 * C + gcU];
                half8 g7 = Grow[a7 * C + gcU];
#pragma unroll
                for (int q = 0; q < 8; ++q)
                    acc[q] += (((float)g0[q] + (float)g1[q]) + ((float)g2[q] + (float)g3[q]))
                            + (((float)g4[q] + (float)g5[q]) + ((float)g6[q] + (float)g7[q]));
            }
            float di = dinv[row];
#pragma unroll
            for (int q = 0; q < 8; ++q) acc[q] *= di;
        }
        half8 hv;
#pragma unroll
        for (int q = 0; q < 8; ++q) hv[q] = (half_t)acc[q];
        *(half8*)&S.g.X16[lrow * XPA + gc * 8] = hv;
    }
    __syncthreads();

    // ---- GEMM 64->128 via MFMA: wave wv owns cols [wv*32, wv*32+32) ----
    // A from LDS X16; B from global w3t [c][k] half, pitch 64 halfs
    f32x4 acc3[2][2];               // [mt][nt]
#pragma unroll
    for (int mt = 0; mt < 2; ++mt)
#pragma unroll
        for (int nt = 0; nt < 2; ++nt) acc3[mt][nt] = f32x4{0.f, 0.f, 0.f, 0.f};
    {
        const half8* W3r = (const half8*)w3t;        // 8 half8 per col row
#pragma unroll
        for (int ks = 0; ks < 2; ++ks) {
            half8 a0 = *(const half8*)&S.g.X16[lr * XPA + ks * 32 + kq * 8];
            half8 a1 = *(const half8*)&S.g.X16[(lr + 16) * XPA + ks * 32 + kq * 8];
            half8 b0 = W3r[(wv * 32 + lr) * 8 + ks * 4 + kq];
            half8 b1 = W3r[(wv * 32 + 16 + lr) * 8 + ks * 4 + kq];
            acc3[0][0] = __builtin_amdgcn_mfma_f32_16x16x32_f16(a0, b0, acc3[0][0], 0, 0, 0);
            acc3[0][1] = __builtin_amdgcn_mfma_f32_16x16x32_f16(a0, b1, acc3[0][1], 0, 0, 0);
            acc3[1][0] = __builtin_amdgcn_mfma_f32_16x16x32_f16(a1, b0, acc3[1][0], 0, 0, 0);
            acc3[1][1] = __builtin_amdgcn_mfma_f32_16x16x32_f16(a1, b1, acc3[1][1], 0, 0, 0);
        }
    }
    const float bc30 = b[wv * 32 + lr];
    const float bc31 = b[wv * 32 + 16 + lr];
    __syncthreads();                 // all g-union reads complete

    // ---- X3 tile (f16) ----
#pragma unroll
    for (int mt = 0; mt < 2; ++mt)
#pragma unroll
        for (int nt = 0; nt < 2; ++nt) {
            float bb = nt ? bc31 : bc30;
#pragma unroll
            for (int j = 0; j < 4; ++j) {
                float v = fmaxf(acc3[mt][nt][j] + bb, 0.f);
                S.h.X3[(mt * 16 + kq * 4 + j) * XPB + wv * 32 + nt * 16 + lr] = (half_t)v;
            }
        }
    __syncthreads();

    // ---- head stage 1: 128 -> 64 via MFMA: wave wv owns cols [wv*16, wv*16+16) ----
    // A from LDS X3; B from global w1t [c][k] half, pitch 128 halfs
    f32x4 h1a[2];
    h1a[0] = f32x4{0.f, 0.f, 0.f, 0.f};
    h1a[1] = f32x4{0.f, 0.f, 0.f, 0.f};
    {
        const half8* W1r = (const half8*)w1t;        // 16 half8 per col row
#pragma unroll
        for (int ks = 0; ks < 4; ++ks) {
            half8 a0 = *(const half8*)&S.h.X3[lr * XPB + ks * 32 + kq * 8];
            half8 a1 = *(const half8*)&S.h.X3[(lr + 16) * XPB + ks * 32 + kq * 8];
            half8 bb = W1r[(wv * 16 + lr) * 16 + ks * 4 + kq];
            h1a[0] = __builtin_amdgcn_mfma_f32_16x16x32_f16(a0, bb, h1a[0], 0, 0, 0);
            h1a[1] = __builtin_amdgcn_mfma_f32_16x16x32_f16(a1, bb, h1a[1], 0, 0, 0);
        }
    }
    {
        float bb = bl1[wv * 16 + lr];
#pragma unroll
        for (int mt = 0; mt < 2; ++mt)
#pragma unroll
            for (int j = 0; j < 4; ++j)
                S.h.h1[(mt * 16 + kq * 4 + j) * 65 + wv * 16 + lr] =
                    fmaxf(h1a[mt][j] + bb, 0.f);
    }
    __syncthreads();

    // ---- head stage 2: 64 -> 32 (weights fp32 straight from L2) ----
    {
        const int c4 = tid & 7;
        const int rl = tid >> 3;          // 32 rows, 1 each
        float a2[4] = {0.f, 0.f, 0.f, 0.f};
#pragma unroll 4
        for (int k = 0; k < 64; ++k) {
            float4 w = ((const float4*)Wl2)[k * 8 + c4];
            float xs = S.h.h1[rl * 65 + k];
            a2[0] += xs * w.x; a2[1] += xs * w.y;
            a2[2] += xs * w.z; a2[3] += xs * w.w;
        }
        float4 bc = ((const float4*)bl2)[c4];
        S.h.h2[rl * 33 + c4 * 4 + 0] = fmaxf(a2[0] + bc.x, 0.f);
        S.h.h2[rl * 33 + c4 * 4 + 1] = fmaxf(a2[1] + bc.y, 0.f);
        S.h.h2[rl * 33 + c4 * 4 + 2] = fmaxf(a2[2] + bc.z, 0.f);
        S.h.h2[rl * 33 + c4 * 4 + 3] = fmaxf(a2[3] + bc.w, 0.f);
    }
    __syncthreads();

    // ---- head stage 3: 32 -> 16 (first 128 threads) ----
    {
        const int c4 = tid & 3;
        const int rl = tid >> 2;
        if (rl < TM) {
            float s0 = 0.f, s1 = 0.f, s2 = 0.f, s3 = 0.f;
#pragma unroll 4
            for (int k = 0; k < 32; ++k) {
                float4 w = ((const float4*)Wl3)[k * 4 + c4];
                float xs = S.h.h2[rl * 33 + k];
                s0 += xs * w.x; s1 += xs * w.y;
                s2 += xs * w.z; s3 += xs * w.w;
            }
            int row = r0 + rl;
            if (row < n) {
                float4 bc = ((const float4*)bl3)[c4];
                float4 o;
                o.x = fmaxf(s0 + bc.x, 0.f);
                o.y = fmaxf(s1 + bc.y, 0.f);
                o.z = fmaxf(s2 + bc.z, 0.f);
                o.w = fmaxf(s3 + bc.w, 0.f);
                ((float4*)out)[(size_t)row * 4 + c4] = o;
            }
        }
    }
}

extern "C" void kernel_launch(void* const* d_in, const int* in_sizes, int n_in,
                              void* d_out, int out_size, void* d_ws, size_t ws_size,
                              hipStream_t stream) {
    const float* x   = (const float*)d_in[0];
    const int*   ei  = (const int*)d_in[1];
    const float* W1  = (const float*)d_in[2];
    const float* bb1 = (const float*)d_in[3];
    const float* W2  = (const float*)d_in[4];
    const float* bb2 = (const float*)d_in[5];
    const float* W3  = (const float*)d_in[6];
    const float* bb3 = (const float*)d_in[7];
    const float* Wl1 = (const float*)d_in[8];
    const float* bl1 = (const float*)d_in[9];
    const float* Wl2 = (const float*)d_in[10];
    const float* bl2 = (const float*)d_in[11];
    const float* Wl3 = (const float*)d_in[12];
    const float* bl3 = (const float*)d_in[13];
    float* out = (float*)d_out;

    const int n = in_sizes[0] / 16;   // 50000
    const int e = in_sizes[1] / 2;    // 800000
    const int* src = ei;
    const int* dst = ei + e;
    const int nb = cdiv(n, 256);      // 196 coarse buckets

    char* p = (char*)d_ws;
    auto alloc = [&](size_t bytes) {
        char* r = p;
        p += (bytes + 255) & ~(size_t)255;
        return r;
    };
    int*            bcur = (int*)           alloc(1024);                  // 256 ints
    int*            ncnt = (int*)           alloc((size_t)nb * 256 * 4); // contiguous after bcur
    float*          dinv = (float*)         alloc((size_t)n * 4);
    int*            offs = (int*)           alloc((size_t)n * 4);
    unsigned short* nch  = (unsigned short*)alloc((size_t)n * 2);
    unsigned int*   gbuf = (unsigned int*)  alloc((size_t)nb * MAXB * 4);
    unsigned short* ssrc = (unsigned short*)alloc((size_t)nb * MAXB * 2);
    half_t*         H1   = (half_t*)        alloc((size_t)(n + 1) * 64 * 2); // G16/G64
    half_t*         H2   = (half_t*)        alloc((size_t)(n + 1) * 32 * 2);
    half_t*         w3t  = (half_t*)        alloc(128 * 64 * 2);  // W3^T half [c][k]
    half_t*         w1t  = (half_t*)        alloc(64 * 128 * 2);  // Wl1^T half [c][k]

    hipMemsetAsync(bcur, 0, 1024 + (size_t)nb * 256 * 4, stream);
    k_wprep<<<2, TPB, 0, stream>>>(W3, Wl1, w3t, w1t);
    k_binscatter<<<cdiv(e, TE), TPB, 0, stream>>>(src, dst, bcur, ncnt, gbuf, e, nb);
    k_csr<<<nb, TPB, 0, stream>>>(gbuf, bcur, ncnt, x, offs, nch, dinv, ssrc, H1, n, nb);

    k_conv<16, 32, 4, true, true, false, true><<<cdiv(n, 128), TPB, 0, stream>>>(
        offs, nch, ssrc, H1, dinv, W1, bb1, H2, n);
    k_conv<32, 64, 4, true, true, false, true><<<cdiv(n, 64), TPB, 0, stream>>>(
        offs, nch, ssrc, H2, dinv, W2, bb2, H1, n);
    k_conv3_head<<<cdiv(n, 32), TPB, 0, stream>>>(
        offs, nch, ssrc, H1, dinv, w3t, bb3, w1t, bl1, Wl2, bl2, Wl3, bl3, out, n);
}

// Round 8
// 254.199 us; speedup vs baseline: 1.0710x; 1.0710x over previous
//
#include <hip/hip_runtime.h>

#define TPB 256
#define TE  2048      // edges per binscatter block
#define MAXB 6144     // fixed bucket capacity (mean 4081, 32 sigma headroom); mult of 8

typedef _Float16 half_t;
typedef _Float16 half4 __attribute__((ext_vector_type(4)));
typedef _Float16 half8 __attribute__((ext_vector_type(8)));
typedef float float8v __attribute__((ext_vector_type(8)));
typedef float f32x4 __attribute__((ext_vector_type(4)));

static inline int cdiv(int a, int b) { return (a + b - 1) / b; }

// r5: scattered 4B stores ~16x write-amplified -> contiguous runs only.
// r12: fixed-capacity buckets kill histogram+scans.
// r14: software grid barriers cost ~100us (L2 wb/inv, non-coherent XCD L2s).
// r15: conv3_head VALU matmul -> MFMA f32_16x16x32_f16 (62.8 -> 45.4us).
// r16: 9.4M LDS conflicts were per-block weight-transpose staging -> global
//      pre-transposed half [col][k] tables (k_wprep).
// r18: edge order = atomic arrival order -> fp32 sum order -> f16 rounding
//      flips (4.9e-4..2.9e-3 across schedules). Canonical per-node sort in
//      k_csr makes the whole pipeline bit-deterministic.
// r19 (R7 counters): two regressions. (a) insertion sort = DEPENDENT LDS
//      chain at ~130cyc/step with csr's 1-wave/SIMD grid (no latency hiding)
//      ~= +35us -> counting-rank sort (d^2 INDEPENDENT reads, ~6cyc pipelined).
//      (b) bounds(256,6) occupancy 30->47% thrashed per-XCD L2 (H1 table
//      6.4MB > 4MB/XCD): FETCH 29->75MB -> revert conv3_head to bounds(256,4).

// one-time weight transpose+convert to half [col][k]; 2 uniform blocks
__global__ void __launch_bounds__(TPB)
k_wprep(const float* __restrict__ W3, const float* __restrict__ Wl1,
        half_t* __restrict__ w3t, half_t* __restrict__ w1t) {
    const int tid = threadIdx.x;
    if (blockIdx.x == 0) {
        for (int t = tid; t < 128 * 16; t += TPB) {       // W3: 64k x 128c
            int c = t >> 4, k4 = t & 15;
            half4 h;
#pragma unroll
            for (int i = 0; i < 4; ++i) h[i] = (half_t)W3[(k4 * 4 + i) * 128 + c];
            *(half4*)&w3t[c * 64 + k4 * 4] = h;
        }
    } else {
        for (int t = tid; t < 64 * 32; t += TPB) {        // Wl1: 128k x 64c
            int c = t >> 5, k4 = t & 31;
            half4 h;
#pragma unroll
            for (int i = 0; i < 4; ++i) h[i] = (half_t)Wl1[(k4 * 4 + i) * 64 + c];
            *(half4*)&w1t[c * 128 + k4 * 4] = h;
        }
    }
}

__global__ void __launch_bounds__(TPB)
k_binscatter(const int* __restrict__ src, const int* __restrict__ dst,
             int* __restrict__ bcur, int* __restrict__ ncnt,
             unsigned int* __restrict__ gbuf, int e, int nb) {
    __shared__ int lcnt[256], loffs[256], lcur[256], gres[256];
    __shared__ int ss[256];
    __shared__ unsigned int ldata[TE];
    const int tid = threadIdx.x;
    const int base = blockIdx.x * TE;
    const int cnt = min(TE, e - base);
    lcnt[tid] = 0;
    __syncthreads();

    unsigned int myv[TE / TPB];
    int myb[TE / TPB];
#pragma unroll
    for (int k = 0; k < TE / TPB; ++k) {
        int j = tid + k * TPB;
        if (j < cnt) {
            int d = dst[base + j], s = src[base + j];
            int b = d >> 8;
            myv[k] = ((unsigned)b << 24) | ((unsigned)(d & 255) << 16) | (unsigned)s;
            myb[k] = b;
            atomicAdd(&lcnt[b], 1);
            atomicAdd(&ncnt[d], 1);          // global per-node in-degree
        } else myb[k] = -1;
    }
    __syncthreads();
    {
        int v = lcnt[tid];
        ss[tid] = v;
        __syncthreads();
        for (int d = 1; d < 256; d <<= 1) {
            int x2 = (tid >= d) ? ss[tid - d] : 0;
            __syncthreads();
            ss[tid] += x2;
            __syncthreads();
        }
        loffs[tid] = ss[tid] - v;
        lcur[tid] = ss[tid] - v;
    }
    __syncthreads();
    if (tid < nb && lcnt[tid])
        gres[tid] = tid * MAXB + atomicAdd(&bcur[tid], lcnt[tid]);
#pragma unroll
    for (int k = 0; k < TE / TPB; ++k) {
        if (myb[k] >= 0) {
            int p = atomicAdd(&lcur[myb[k]], 1);
            ldata[p] = myv[k];
        }
    }
    __syncthreads();
    for (int j = tid; j < cnt; j += TPB) {        // contiguous per-bucket runs
        unsigned int v = ldata[j];
        int b = v >> 24;
        gbuf[gres[b] + (j - loffs[b])] = v & 0xFFFFFFu;
    }
}

// per-bucket CSR from precomputed degrees: ONE pass over bucket edges.
// r18/r19: per-node canonical order via counting-rank sort (independent LDS
// reads pipeline; no dependent chain -> cheap even at 1 wave/SIMD).
__global__ void __launch_bounds__(TPB)
k_csr(const unsigned int* __restrict__ gbuf, const int* __restrict__ bcur,
      const int* __restrict__ ncnt, const float* __restrict__ x,
      int* __restrict__ offs, unsigned short* __restrict__ nch,
      float* __restrict__ dinv, unsigned short* __restrict__ ssrc,
      half_t* __restrict__ G, int n, int nb) {
    __shared__ int ss[256], lcur2[256];
    __shared__ float sdinv[256];
    __shared__ unsigned short stage[MAXB];
    __shared__ unsigned short stage2[MAXB];
    const int b = blockIdx.x;
    const int t = threadIdx.x;
    const int s0 = b * MAXB;
    const int m = bcur[b];

    const int v = ncnt[b * 256 + t];              // in-degree (excl self-loop)
    const int pv = (v + 7) & ~7;                  // pad to 8
    ss[t] = pv;
    __syncthreads();
    for (int d = 1; d < 256; d <<= 1) {
        int x2 = (t >= d) ? ss[t - d] : 0;
        __syncthreads();
        ss[t] += x2;
        __syncthreads();
    }
    const int lo = ss[t] - pv;
    lcur2[t] = lo;
    float di = rsqrtf((float)v + 1.0f);           // +1 self-loop
    sdinv[t] = di;
    int node = b * 256 + t;
    if (node < n) {
        offs[node] = s0 + lo;
        nch[node] = (unsigned short)(pv >> 3);
        dinv[node] = di;
    }
    __syncthreads();
    for (int j = t; j < m; j += TPB) {
        unsigned int u = gbuf[s0 + j];
        int p = atomicAdd(&lcur2[(u >> 16) & 255], 1);
        stage[p] = (unsigned short)(u & 0xFFFFu);
    }
    __syncthreads();
    {   // canonical ascending order via counting-rank (stable: tie-break j<i).
        // d^2 INDEPENDENT LDS reads -> pipelined, no dependent chain (r19).
        for (int i = 0; i < v; ++i) {
            unsigned short ki = stage[lo + i];
            int rank = 0;
            for (int j = 0; j < v; ++j) {
                unsigned short kj = stage[lo + j];
                rank += (kj < ki) | ((kj == ki) & (j < i));
            }
            stage2[lo + rank] = ki;
        }
        for (int q = v; q < pv; ++q)              // sentinel-fill padding
            stage2[lo + q] = (unsigned short)n;
    }
    __syncthreads();
    const int tot = ss[255];
    for (int j = t; j < tot; j += TPB) ssrc[s0 + j] = stage2[j];

    // fused scale: G16[node] = x[node] * dinv[node], fp32 -> fp16
    const int base = b * 256;
    const int cn = min(256, n - base);
    const float4* X4 = (const float4*)x;
    half4* G4 = (half4*)G;
    for (int j = t; j < cn * 4; j += TPB) {
        int nl = j >> 2, k4 = j & 3;
        float4 vv = X4[(size_t)(base + nl) * 4 + k4];
        float d = sdinv[nl];
        half4 h;
        h.x = (half_t)(vv.x * d); h.y = (half_t)(vv.y * d);
        h.z = (half_t)(vv.z * d); h.w = (half_t)(vv.w * d);
        G4[(size_t)(base + nl) * 4 + k4] = h;
    }
    if (b == 0 && t < 4) G4[(size_t)n * 4 + t] = half4{0, 0, 0, 0};  // sentinel row
}

// ---------------- fused gather + GEMM conv (conv1, conv2) ----------------
template<int DI, int DO, int R, bool SCALE, bool OUT_HALF, bool WHALF, bool ZSENT>
__global__ void __launch_bounds__(TPB, 4)
k_conv(const int* __restrict__ offs, const unsigned short* __restrict__ nch,
       const unsigned short* __restrict__ ssrc,
       const half_t* __restrict__ G, const float* __restrict__ dinv,
       const float* __restrict__ W, const float* __restrict__ b,
       void* __restrict__ outp, int n) {
    constexpr int CT = DO / 4;
    constexpr int RT = TPB / CT;
    constexpr int TM = RT * R;
    constexpr int K4 = DI / 4;
    constexpr int PX = K4 + 1;
    constexpr int C  = DI / 8;
    static_assert(TM * C == TPB, "gather/gemm tile mismatch");
    __shared__ float4 sW4[WHALF ? 1 : DI * CT];
    __shared__ half4  sWh[WHALF ? DI * CT : 1];
    __shared__ float4 sX4[TM * PX];
    __shared__ int soffs[TM];
    __shared__ unsigned short snch[TM];
    const int tid = threadIdx.x;
    const int r0 = blockIdx.x * TM;

    const float4* Wg = (const float4*)W;
    for (int t = tid; t < DI * CT; t += TPB) {
        float4 w = Wg[t];
        if (WHALF) {
            half4 h;
            h.x = (half_t)w.x; h.y = (half_t)w.y;
            h.z = (half_t)w.z; h.w = (half_t)w.w;
            sWh[t] = h;
        } else {
            sW4[t] = w;
        }
    }
    if (tid < TM) {
        int row = r0 + tid;
        soffs[tid] = (row < n) ? offs[row] : 0;
        snch[tid] = (row < n) ? nch[row] : (unsigned short)0;
    }
    __syncthreads();

    {   // ---- gather ----
        int lrow = tid / C;
        int gc = tid - lrow * C;
        int row = r0 + lrow;
        float8v acc;
#pragma unroll
        for (int q = 0; q < 8; ++q) acc[q] = 0.f;
        if (row < n) {
            const half8* Grow = (const half8*)G;
            const unsigned gcU = (unsigned)gc;
            half8 hs = Grow[(unsigned)row * C + gcU];
#pragma unroll
            for (int q = 0; q < 8; ++q) acc[q] = (float)hs[q];
            const int nchunks = snch[lrow];
            const uint4* sv = (const uint4*)(ssrc + soffs[lrow]);
            int k = 0;
            for (; k + 2 <= nchunks; k += 2) {
                uint4 pa = sv[k];
                uint4 pb = sv[k + 1];
                unsigned a0 = pa.x & 0xFFFFu, a1 = pa.x >> 16;
                unsigned a2 = pa.y & 0xFFFFu, a3 = pa.y >> 16;
                unsigned a4 = pa.z & 0xFFFFu, a5 = pa.z >> 16;
                unsigned a6 = pa.w & 0xFFFFu, a7 = pa.w >> 16;
                unsigned b0 = pb.x & 0xFFFFu, b1 = pb.x >> 16;
                unsigned b2 = pb.y & 0xFFFFu, b3 = pb.y >> 16;
                unsigned b4 = pb.z & 0xFFFFu, b5 = pb.z >> 16;
                unsigned b6 = pb.w & 0xFFFFu, b7 = pb.w >> 16;
                half8 ga0 = Grow[a0 * C + gcU];
                half8 ga1 = Grow[a1 * C + gcU];
                half8 ga2 = Grow[a2 * C + gcU];
                half8 ga3 = Grow[a3 * C + gcU];
                half8 ga4 = Grow[a4 * C + gcU];
                half8 ga5 = Grow[a5 * C + gcU];
                half8 ga6 = Grow[a6 * C + gcU];
                half8 ga7 = Grow[a7 * C + gcU];
                half8 gb0 = Grow[b0 * C + gcU];
                half8 gb1 = Grow[b1 * C + gcU];
                half8 gb2 = Grow[b2 * C + gcU];
                half8 gb3 = Grow[b3 * C + gcU];
                half8 gb4 = Grow[b4 * C + gcU];
                half8 gb5 = Grow[b5 * C + gcU];
                half8 gb6 = Grow[b6 * C + gcU];
                half8 gb7 = Grow[b7 * C + gcU];
#pragma unroll
                for (int q = 0; q < 8; ++q)
                    acc[q] += (((((float)ga0[q] + (float)ga1[q]) + ((float)ga2[q] + (float)ga3[q]))
                             +  (((float)ga4[q] + (float)ga5[q]) + ((float)ga6[q] + (float)ga7[q])))
                             + ((((float)gb0[q] + (float)gb1[q]) + ((float)gb2[q] + (float)gb3[q]))
                             +  (((float)gb4[q] + (float)gb5[q]) + ((float)gb6[q] + (float)gb7[q]))));
            }
            if (k < nchunks) {
                uint4 pk = sv[k];
                unsigned a0 = pk.x & 0xFFFFu, a1 = pk.x >> 16;
                unsigned a2 = pk.y & 0xFFFFu, a3 = pk.y >> 16;
                unsigned a4 = pk.z & 0xFFFFu, a5 = pk.z >> 16;
                unsigned a6 = pk.w & 0xFFFFu, a7 = pk.w >> 16;
                half8 g0 = Grow[a0 * C + gcU];
                half8 g1 = Grow[a1 * C + gcU];
                half8 g2 = Grow[a2 * C + gcU];
                half8 g3 = Grow[a3 * C + gcU];
                half8 g4 = Grow[a4 * C + gcU];
                half8 g5 = Grow[a5 * C + gcU];
                half8 g6 = Grow[a6 * C + gcU];
                half8 g7 = Grow[a7 * C + gcU];
#pragma unroll
                for (int q = 0; q < 8; ++q)
                    acc[q] += (((float)g0[q] + (float)g1[q]) + ((float)g2[q] + (float)g3[q]))
                            + (((float)g4[q] + (float)g5[q]) + ((float)g6[q] + (float)g7[q]));
            }
            float di = dinv[row];
#pragma unroll
            for (int q = 0; q < 8; ++q) acc[q] *= di;
        }
        sX4[lrow * PX + 2 * gc]     = make_float4(acc[0], acc[1], acc[2], acc[3]);
        sX4[lrow * PX + 2 * gc + 1] = make_float4(acc[4], acc[5], acc[6], acc[7]);
    }
    __syncthreads();

    // ---- GEMM ----
    const int c = tid & (CT - 1);
    const int rg = tid / CT;
    const int rbase = rg * R;
    float4 acc[R];
#pragma unroll
    for (int r = 0; r < R; ++r) acc[r] = make_float4(0.f, 0.f, 0.f, 0.f);
#pragma unroll 2
    for (int k4 = 0; k4 < K4; ++k4) {
        float4 xv[R];
#pragma unroll
        for (int r = 0; r < R; ++r) xv[r] = sX4[(rbase + r) * PX + k4];
#pragma unroll
        for (int kk = 0; kk < 4; ++kk) {
            float4 wv;
            if (WHALF) {
                half4 wh = sWh[(k4 * 4 + kk) * CT + c];
                wv = make_float4((float)wh.x, (float)wh.y, (float)wh.z, (float)wh.w);
            } else {
                wv = sW4[(k4 * 4 + kk) * CT + c];
            }
#pragma unroll
            for (int r = 0; r < R; ++r) {
                float xs = (kk == 0) ? xv[r].x : (kk == 1) ? xv[r].y
                         : (kk == 2) ? xv[r].z : xv[r].w;
                acc[r].x += xs * wv.x; acc[r].y += xs * wv.y;
                acc[r].z += xs * wv.z; acc[r].w += xs * wv.w;
            }
        }
    }

    float4 bc = ((const float4*)b)[c];
#pragma unroll
    for (int r = 0; r < R; ++r) {
        int row = r0 + rbase + r;
        if (row < n) {
            float4 o;
            o.x = fmaxf(acc[r].x + bc.x, 0.f);
            o.y = fmaxf(acc[r].y + bc.y, 0.f);
            o.z = fmaxf(acc[r].z + bc.z, 0.f);
            o.w = fmaxf(acc[r].w + bc.w, 0.f);
            if (SCALE) {
                float d = dinv[row];
                o.x *= d; o.y *= d; o.z *= d; o.w *= d;
            }
            if (OUT_HALF) {
                half4 h;
                h.x = (half_t)o.x; h.y = (half_t)o.y;
                h.z = (half_t)o.z; h.w = (half_t)o.w;
                ((half4*)outp)[(size_t)row * CT + c] = h;
            } else {
                ((float4*)outp)[(size_t)row * CT + c] = o;
            }
        }
    }
    if (ZSENT && OUT_HALF && blockIdx.x == 0 && tid < CT)
        ((half4*)outp)[(size_t)n * CT + tid] = half4{0, 0, 0, 0};
}

// ---------------- conv3 (64->128, MFMA) + fused dense head (stage1 MFMA) ----------------
// B fragments from pre-transposed global half tables (L2 broadcast).
// r19: bounds back to (256,4) -- occupancy 47% thrashed per-XCD L2 on the
// gather (H1 6.4MB > 4MB/XCD; FETCH 29->75MB at bounds(,6)).
__global__ void __launch_bounds__(TPB, 4)
k_conv3_head(const int* __restrict__ offs, const unsigned short* __restrict__ nch,
             const unsigned short* __restrict__ ssrc,
             const half_t* __restrict__ G, const float* __restrict__ dinv,
             const half_t* __restrict__ w3t, const float* __restrict__ b,
             const half_t* __restrict__ w1t, const float* __restrict__ bl1,
             const float* __restrict__ Wl2, const float* __restrict__ bl2,
             const float* __restrict__ Wl3, const float* __restrict__ bl3,
             float* __restrict__ out, int n) {
    constexpr int TM = 32;           // rows per block
    constexpr int C  = 8;            // gather: half8 chunks per 64-dim row
    constexpr int XPA = 72;          // X16 pitch (halfs): 144B
    constexpr int XPB = 136;         // X3 pitch (halfs): 272B
    __shared__ __align__(16) union {
        struct { half_t X16[TM * XPA]; } g;                               // 4.6 KB
        struct { half_t X3[TM * XPB]; float h1[TM * 65]; float h2[TM * 33]; } h; // 21.2 KB
    } S;
    __shared__ int soffs[TM];
    __shared__ unsigned short snch[TM];
    const int tid = threadIdx.x;
    const int r0 = blockIdx.x * TM;
    const int lane = tid & 63;
    const int wv = tid >> 6;         // wave 0..3
    const int lr = lane & 15;        // A-row / B-col / D-col index
    const int kq = lane >> 4;        // k-quarter

    if (tid < TM) {
        int row = r0 + tid;
        soffs[tid] = (row < n) ? offs[row] : 0;
        snch[tid] = (row < n) ? nch[row] : (unsigned short)0;
    }
    __syncthreads();

    {   // ---- gather (DI=64) -> X16 f16 ----
        int lrow = tid / C;
        int gc = tid - lrow * C;
        int row = r0 + lrow;
        float8v acc;
#pragma unroll
        for (int q = 0; q < 8; ++q) acc[q] = 0.f;
        if (row < n) {
            const half8* Grow = (const half8*)G;
            const unsigned gcU = (unsigned)gc;
            half8 hs = Grow[(unsigned)row * C + gcU];
#pragma unroll
            for (int q = 0; q < 8; ++q) acc[q] = (float)hs[q];
            const int nchunks = snch[lrow];
            const uint4* sv = (const uint4*)(ssrc + soffs[lrow]);
            int k = 0;
            for (; k + 2 <= nchunks; k += 2) {
                uint4 pa = sv[k];
                uint4 pb = sv[k + 1];
                unsigned a0 = pa.x & 0xFFFFu, a1 = pa.x >> 16;
                unsigned a2 = pa.y & 0xFFFFu, a3 = pa.y >> 16;
                unsigned a4 = pa.z & 0xFFFFu, a5 = pa.z >> 16;
                unsigned a6 = pa.w & 0xFFFFu, a7 = pa.w >> 16;
                unsigned b0 = pb.x & 0xFFFFu, b1 = pb.x >> 16;
                unsigned b2 = pb.y & 0xFFFFu, b3 = pb.y >> 16;
                unsigned b4 = pb.z & 0xFFFFu, b5 = pb.z >> 16;
                unsigned b6 = pb.w & 0xFFFFu, b7 = pb.w >> 16;
                half8 ga0 = Grow[a0 * C + gcU];
                half8 ga1 = Grow[a1 * C + gcU];
                half8 ga2 = Grow[a2 * C + gcU];
                half8 ga3 = Grow[a3 * C + gcU];
                half8 ga4 = Grow[a4 * C + gcU];
                half8 ga5 = Grow[a5 * C + gcU];
                half8 ga6 = Grow[a6 * C + gcU];
                half8 ga7 = Grow[a7 * C + gcU];
                half8 gb0 = Grow[b0 * C + gcU];
                half8 gb1 = Grow[b1 * C + gcU];
                half8 gb2 = Grow[b2 * C + gcU];
                half8 gb3 = Grow[b3 * C + gcU];
                half8 gb4 = Grow[b4 * C + gcU];
                half8 gb5 = Grow[b5 * C + gcU];
                half8 gb6 = Grow[b6 * C + gcU];
                half8 gb7 = Grow[b7 * C + gcU];
#pragma unroll
                for (int q = 0; q < 8; ++q)
                    acc[q] += (((((float)ga0[q] + (float)ga1[q]) + ((float)ga2[q] + (float)ga3[q]))
                             +  (((float)ga4[q] + (float)ga5[q]) + ((float)ga6[q] + (float)ga7[q])))
                             + ((((float)gb0[q] + (float)gb1[q]) + ((float)gb2[q] + (float)gb3[q]))
                             +  (((float)gb4[q] + (float)gb5[q]) + ((float)gb6[q] + (float)gb7[q]))));
            }
            if (k < nchunks) {
                uint4 pk = sv[k];
                unsigned a0 = pk.x & 0xFFFFu, a1 = pk.x >> 16;
                unsigned a2 = pk.y & 0xFFFFu, a3 = pk.y >> 16;
                unsigned a4 = pk.z & 0xFFFFu, a5 = pk.z >> 16;
                unsigned a6 = pk.w & 0xFFFFu, a7 = pk.w >> 16;
                half8 g0 = Grow[a0 * C + gcU];
                half8 g1 = Grow[a1 * C + gcU];
                half8 g2 = Grow[a2 * C + gcU];
                half8 g3 = Grow[a3 * C + gcU];
                half8 g4 = Grow[a4 * C + gcU];
                half8 g5 = Grow[a5 * C + gcU];
                half8 g6 = Grow[a6 * C + gcU];
                half8 g7 = Grow[a7 * C + gcU];
#pragma unroll
                for (int q = 0; q < 8; ++q)
                    acc[q] += (((float)g0[q] + (float)g1[q]) + ((float)g2[q] + (float)g3[q]))
                            + (((float)g4[q] + (float)g5[q]) + ((float)g6[q] + (float)g7[q]));
            }
            float di = dinv[row];
#pragma unroll
            for (int q = 0; q < 8; ++q) acc[q] *= di;
        }
        half8 hv;
#pragma unroll
        for (int q = 0; q < 8; ++q) hv[q] = (half_t)acc[q];
        *(half8*)&S.g.X16[lrow * XPA + gc * 8] = hv;
    }
    __syncthreads();

    // ---- GEMM 64->128 via MFMA: wave wv owns cols [wv*32, wv*32+32) ----
    // A from LDS X16; B from global w3t [c][k] half, pitch 64 halfs
    f32x4 acc3[2][2];               // [mt][nt]
#pragma unroll
    for (int mt = 0; mt < 2; ++mt)
#pragma unroll
        for (int nt = 0; nt < 2; ++nt) acc3[mt][nt] = f32x4{0.f, 0.f, 0.f, 0.f};
    {
        const half8* W3r = (const half8*)w3t;        // 8 half8 per col row
#pragma unroll
        for (int ks = 0; ks < 2; ++ks) {
            half8 a0 = *(const half8*)&S.g.X16[lr * XPA + ks * 32 + kq * 8];
            half8 a1 = *(const half8*)&S.g.X16[(lr + 16) * XPA + ks * 32 + kq * 8];
            half8 b0 = W3r[(wv * 32 + lr) * 8 + ks * 4 + kq];
            half8 b1 = W3r[(wv * 32 + 16 + lr) * 8 + ks * 4 + kq];
            acc3[0][0] = __builtin_amdgcn_mfma_f32_16x16x32_f16(a0, b0, acc3[0][0], 0, 0, 0);
            acc3[0][1] = __builtin_amdgcn_mfma_f32_16x16x32_f16(a0, b1, acc3[0][1], 0, 0, 0);
            acc3[1][0] = __builtin_amdgcn_mfma_f32_16x16x32_f16(a1, b0, acc3[1][0], 0, 0, 0);
            acc3[1][1] = __builtin_amdgcn_mfma_f32_16x16x32_f16(a1, b1, acc3[1][1], 0, 0, 0);
        }
    }
    const float bc30 = b[wv * 32 + lr];
    const float bc31 = b[wv * 32 + 16 + lr];
    __syncthreads();                 // all g-union reads complete

    // ---- X3 tile (f16) ----
#pragma unroll
    for (int mt = 0; mt < 2; ++mt)
#pragma unroll
        for (int nt = 0; nt < 2; ++nt) {
            float bb = nt ? bc31 : bc30;
#pragma unroll
            for (int j = 0; j < 4; ++j) {
                float v = fmaxf(acc3[mt][nt][j] + bb, 0.f);
                S.h.X3[(mt * 16 + kq * 4 + j) * XPB + wv * 32 + nt * 16 + lr] = (half_t)v;
            }
        }
    __syncthreads();

    // ---- head stage 1: 128 -> 64 via MFMA: wave wv owns cols [wv*16, wv*16+16) ----
    // A from LDS X3; B from global w1t [c][k] half, pitch 128 halfs
    f32x4 h1a[2];
    h1a[0] = f32x4{0.f, 0.f, 0.f, 0.f};
    h1a[1] = f32x4{0.f, 0.f, 0.f, 0.f};
    {
        const half8* W1r = (const half8*)w1t;        // 16 half8 per col row
#pragma unroll
        for (int ks = 0; ks < 4; ++ks) {
            half8 a0 = *(const half8*)&S.h.X3[lr * XPB + ks * 32 + kq * 8];
            half8 a1 = *(const half8*)&S.h.X3[(lr + 16) * XPB + ks * 32 + kq * 8];
            half8 bb = W1r[(wv * 16 + lr) * 16 + ks * 4 + kq];
            h1a[0] = __builtin_amdgcn_mfma_f32_16x16x32_f16(a0, bb, h1a[0], 0, 0, 0);
            h1a[1] = __builtin_amdgcn_mfma_f32_16x16x32_f16(a1, bb, h1a[1], 0, 0, 0);
        }
    }
    {
        float bb = bl1[wv * 16 + lr];
#pragma unroll
        for (int mt = 0; mt < 2; ++mt)
#pragma unroll
            for (int j = 0; j < 4; ++j)
                S.h.h1[(mt * 16 + kq * 4 + j) * 65 + wv * 16 + lr] =
                    fmaxf(h1a[mt][j] + bb, 0.f);
    }
    __syncthreads();

    // ---- head stage 2: 64 -> 32 (weights fp32 straight from L2) ----
    {
        const int c4 = tid & 7;
        const int rl = tid >> 3;          // 32 rows, 1 each
        float a2[4] = {0.f, 0.f, 0.f, 0.f};
#pragma unroll 4
        for (int k = 0; k < 64; ++k) {
            float4 w = ((const float4*)Wl2)[k * 8 + c4];
            float xs = S.h.h1[rl * 65 + k];
            a2[0] += xs * w.x; a2[1] += xs * w.y;
            a2[2] += xs * w.z; a2[3] += xs * w.w;
        }
        float4 bc = ((const float4*)bl2)[c4];
        S.h.h2[rl * 33 + c4 * 4 + 0] = fmaxf(a2[0] + bc.x, 0.f);
        S.h.h2[rl * 33 + c4 * 4 + 1] = fmaxf(a2[1] + bc.y, 0.f);
        S.h.h2[rl * 33 + c4 * 4 + 2] = fmaxf(a2[2] + bc.z, 0.f);
        S.h.h2[rl * 33 + c4 * 4 + 3] = fmaxf(a2[3] + bc.w, 0.f);
    }
    __syncthreads();

    // ---- head stage 3: 32 -> 16 (first 128 threads) ----
    {
        const int c4 = tid & 3;
        const int rl = tid >> 2;
        if (rl < TM) {
            float s0 = 0.f, s1 = 0.f, s2 = 0.f, s3 = 0.f;
#pragma unroll 4
            for (int k = 0; k < 32; ++k) {
                float4 w = ((const float4*)Wl3)[k * 4 + c4];
                float xs = S.h.h2[rl * 33 + k];
                s0 += xs * w.x; s1 += xs * w.y;
                s2 += xs * w.z; s3 += xs * w.w;
            }
            int row = r0 + rl;
            if (row < n) {
                float4 bc = ((const float4*)bl3)[c4];
                float4 o;
                o.x = fmaxf(s0 + bc.x, 0.f);
                o.y = fmaxf(s1 + bc.y, 0.f);
                o.z = fmaxf(s2 + bc.z, 0.f);
                o.w = fmaxf(s3 + bc.w, 0.f);
                ((float4*)out)[(size_t)row * 4 + c4] = o;
            }
        }
    }
}

extern "C" void kernel_launch(void* const* d_in, const int* in_sizes, int n_in,
                              void* d_out, int out_size, void* d_ws, size_t ws_size,
                              hipStream_t stream) {
    const float* x   = (const float*)d_in[0];
    const int*   ei  = (const int*)d_in[1];
    const float* W1  = (const float*)d_in[2];
    const float* bb1 = (const float*)d_in[3];
    const float* W2  = (const float*)d_in[4];
    const float* bb2 = (const float*)d_in[5];
    const float* W3  = (const float*)d_in[6];
    const float* bb3 = (const float*)d_in[7];
    const float* Wl1 = (const float*)d_in[8];
    const float* bl1 = (const float*)d_in[9];
    const float* Wl2 = (const float*)d_in[10];
    const float* bl2 = (const float*)d_in[11];
    const float* Wl3 = (const float*)d_in[12];
    const float* bl3 = (const float*)d_in[13];
    float* out = (float*)d_out;

    const int n = in_sizes[0] / 16;   // 50000
    const int e = in_sizes[1] / 2;    // 800000
    const int* src = ei;
    const int* dst = ei + e;
    const int nb = cdiv(n, 256);      // 196 coarse buckets

    char* p = (char*)d_ws;
    auto alloc = [&](size_t bytes) {
        char* r = p;
        p += (bytes + 255) & ~(size_t)255;
        return r;
    };
    int*            bcur = (int*)           alloc(1024);                  // 256 ints
    int*            ncnt = (int*)           alloc((size_t)nb * 256 * 4); // contiguous after bcur
    float*          dinv = (float*)         alloc((size_t)n * 4);
    int*            offs = (int*)           alloc((size_t)n * 4);
    unsigned short* nch  = (unsigned short*)alloc((size_t)n * 2);
    unsigned int*   gbuf = (unsigned int*)  alloc((size_t)nb * MAXB * 4);
    unsigned short* ssrc = (unsigned short*)alloc((size_t)nb * MAXB * 2);
    half_t*         H1   = (half_t*)        alloc((size_t)(n + 1) * 64 * 2); // G16/G64
    half_t*         H2   = (half_t*)        alloc((size_t)(n + 1) * 32 * 2);
    half_t*         w3t  = (half_t*)        alloc(128 * 64 * 2);  // W3^T half [c][k]
    half_t*         w1t  = (half_t*)        alloc(64 * 128 * 2);  // Wl1^T half [c][k]

    hipMemsetAsync(bcur, 0, 1024 + (size_t)nb * 256 * 4, stream);
    k_wprep<<<2, TPB, 0, stream>>>(W3, Wl1, w3t, w1t);
    k_binscatter<<<cdiv(e, TE), TPB, 0, stream>>>(src, dst, bcur, ncnt, gbuf, e, nb);
    k_csr<<<nb, TPB, 0, stream>>>(gbuf, bcur, ncnt, x, offs, nch, dinv, ssrc, H1, n, nb);

    k_conv<16, 32, 4, true, true, false, true><<<cdiv(n, 128), TPB, 0, stream>>>(
        offs, nch, ssrc, H1, dinv, W1, bb1, H2, n);
    k_conv<32, 64, 4, true, true, false, true><<<cdiv(n, 64), TPB, 0, stream>>>(
        offs, nch, ssrc, H2, dinv, W2, bb2, H1, n);
    k_conv3_head<<<cdiv(n, 32), TPB, 0, stream>>>(
        offs, nch, ssrc, H1, dinv, w3t, bb3, w1t, bl1, Wl2, bl2, Wl3, bl3, out, n);
}